// Round 1
// baseline (800.402 us; speedup 1.0000x reference)
//
#include <hip/hip_runtime.h>
#include <hip/hip_bf16.h>

#define N 4096
#define D 128
#define NB 1024          // buckets per row (avg ~4 elements/bucket)
#define T3 256           // threads for row kernel

static constexpr size_t WS_ACC_OFF = 0;       // double acc[2]: {sum_logits, sum_lms}
static constexpr size_t WS_X2_OFF  = 64;      // float x2[N]
static constexpr size_t WS_E_OFF   = 32768;   // bf16 E[N*N] (33.5 MB)

// ---------------- kernel 1: row squared norms ----------------
__global__ void x2_kernel(const float* __restrict__ f, float* __restrict__ x2) {
    int row = blockIdx.x;
    int t = threadIdx.x;
    float a = f[row * D + t];
    float b = f[row * D + t + 64];
    float v = a * a + b * b;
    #pragma unroll
    for (int off = 32; off > 0; off >>= 1) v += __shfl_down(v, off);
    if (t == 0) x2[row] = v;
}

// ---------------- kernel 2: Gram -> e = exp(-dist/2) (bf16), sum logits ----------------
__global__ __launch_bounds__(256) void gram_kernel(const float* __restrict__ f,
                                                   const float* __restrict__ x2,
                                                   __hip_bfloat16* __restrict__ E,
                                                   double* __restrict__ acc) {
    __shared__ __align__(16) float As[64][68];  // 68 = 64+4 pad: float4-aligned rows, low conflict
    __shared__ __align__(16) float Bs[64][68];
    __shared__ float red[256];

    int tx = threadIdx.x, ty = threadIdx.y;
    int tid = ty * 16 + tx;
    int rowBase = blockIdx.y * 64, colBase = blockIdx.x * 64;

    float accv[4][4];
    #pragma unroll
    for (int i = 0; i < 4; i++)
        #pragma unroll
        for (int j = 0; j < 4; j++) accv[i][j] = 0.f;

    for (int kc = 0; kc < D; kc += 64) {
        __syncthreads();
        #pragma unroll
        for (int it = 0; it < 4; it++) {
            int lin4 = tid + it * 256;       // float4 index within 64x64 tile
            int row = lin4 >> 4;             // 16 float4 per row
            int k4 = (lin4 & 15) * 4;
            float4 va = *(const float4*)&f[(size_t)(rowBase + row) * D + kc + k4];
            *(float4*)&As[row][k4] = va;
            float4 vb = *(const float4*)&f[(size_t)(colBase + row) * D + kc + k4];
            *(float4*)&Bs[row][k4] = vb;
        }
        __syncthreads();
        #pragma unroll
        for (int k = 0; k < 64; k += 4) {
            float4 a4[4], b4[4];
            #pragma unroll
            for (int i = 0; i < 4; i++) a4[i] = *(float4*)&As[ty + 16 * i][k];
            #pragma unroll
            for (int j = 0; j < 4; j++) b4[j] = *(float4*)&Bs[tx + 16 * j][k];
            #pragma unroll
            for (int i = 0; i < 4; i++)
                #pragma unroll
                for (int j = 0; j < 4; j++) {
                    accv[i][j] += a4[i].x * b4[j].x;
                    accv[i][j] += a4[i].y * b4[j].y;
                    accv[i][j] += a4[i].z * b4[j].z;
                    accv[i][j] += a4[i].w * b4[j].w;
                }
        }
    }

    float x2i[4], x2j[4];
    #pragma unroll
    for (int i = 0; i < 4; i++) x2i[i] = x2[rowBase + ty + 16 * i];
    #pragma unroll
    for (int j = 0; j < 4; j++) x2j[j] = x2[colBase + tx + 16 * j];

    float sumLogit = 0.f;
    #pragma unroll
    for (int i = 0; i < 4; i++) {
        #pragma unroll
        for (int j = 0; j < 4; j++) {
            int gi = rowBase + ty + 16 * i;
            int gj = colBase + tx + 16 * j;
            float sq = x2i[i] + x2j[j] - 2.f * accv[i][j];
            sq = fmaxf(sq, 0.f);
            float logit = (sq > 0.f) ? (-0.5f * sqrtf(sq)) : 0.f;
            float e = expf(logit);
            if (gi == gj) { e = 0.f; logit = 0.f; }   // diagonal dropped
            sumLogit += logit;
            E[(size_t)gi * N + gj] = __float2bfloat16(e);
        }
    }

    red[tid] = sumLogit;
    __syncthreads();
    #pragma unroll
    for (int s = 128; s > 0; s >>= 1) {
        if (tid < s) red[tid] += red[tid + s];
        __syncthreads();
    }
    if (tid == 0) atomicAdd(&acc[0], (double)red[0]);
}

// ---------------- kernel 3: per-row bucketed masked log-sums (theta + shift) ----------------
__global__ __launch_bounds__(T3) void lms_kernel(const __hip_bfloat16* __restrict__ E,
                                                 const float* __restrict__ theta,
                                                 const float* __restrict__ shift,
                                                 double* __restrict__ acc) {
    __shared__ float e_row[N];             // 16 KB
    __shared__ float d_row[N];             // 16 KB
    __shared__ unsigned short sidx[N];     // 8 KB
    __shared__ int start[NB + 1];          // 4.1 KB
    __shared__ int cursor[NB];             // 4 KB
    __shared__ float bsum[NB];             // 4 KB
    __shared__ int scanI[T3];
    __shared__ float scanF[T3];
    __shared__ float red[T3];

    constexpr int C = NB / T3;  // 4 buckets per thread in scans

    int tid = threadIdx.x;
    int row = blockIdx.x;

    for (int j = tid; j < N; j += T3)
        e_row[j] = __bfloat162float(E[(size_t)row * N + j]);   // diag already 0

    float localSum = 0.f;

    for (int m = 0; m < 2; m++) {
        const float* dmat = m ? shift : theta;
        float scale = m ? ((float)NB / 100.0f) : ((float)NB / 180.0f);

        __syncthreads();  // protect e_row (m=0) / previous pass arrays (m=1)
        for (int j = tid; j < N; j += T3) d_row[j] = dmat[(size_t)row * N + j];
        for (int b = tid; b < NB; b += T3) cursor[b] = 0;
        __syncthreads();

        // 1) histogram
        for (int j = tid; j < N; j += T3) {
            int b = (int)(d_row[j] * scale);
            b = min(max(b, 0), NB - 1);
            atomicAdd(&cursor[b], 1);
        }
        __syncthreads();

        // 2) exclusive prefix scan of counts -> start[], copy to cursor
        int base = tid * C;
        int loc[C];
        int csum = 0;
        #pragma unroll
        for (int q = 0; q < C; q++) { loc[q] = csum; csum += cursor[base + q]; }
        scanI[tid] = csum;
        __syncthreads();
        for (int off = 1; off < T3; off <<= 1) {
            int add = (tid >= off) ? scanI[tid - off] : 0;
            __syncthreads();
            scanI[tid] += add;
            __syncthreads();
        }
        int chunkExcl = scanI[tid] - csum;
        #pragma unroll
        for (int q = 0; q < C; q++) {
            int s = chunkExcl + loc[q];
            start[base + q] = s;
            cursor[base + q] = s;
        }
        if (tid == T3 - 1) start[NB] = scanI[T3 - 1];
        __syncthreads();

        // 3) scatter indices (counting sort)
        for (int j = tid; j < N; j += T3) {
            int b = (int)(d_row[j] * scale);
            b = min(max(b, 0), NB - 1);
            int p = atomicAdd(&cursor[b], 1);
            sidx[p] = (unsigned short)j;
        }
        __syncthreads();

        // 4) per-bucket e sums
        for (int b = tid; b < NB; b += T3) {
            float s = 0.f;
            for (int p = start[b]; p < start[b + 1]; p++) s += e_row[sidx[p]];
            bsum[b] = s;
        }
        __syncthreads();

        // 5) exclusive suffix scan over bsum (bsum[b] <- sum over buckets > b)
        float floc[C];
        float fsum = 0.f;
        #pragma unroll
        for (int q = C - 1; q >= 0; q--) { floc[q] = fsum; fsum += bsum[base + q]; }
        scanF[tid] = fsum;
        __syncthreads();
        for (int off = 1; off < T3; off <<= 1) {
            float add = (tid + off < T3) ? scanF[tid + off] : 0.f;
            __syncthreads();
            scanF[tid] += add;
            __syncthreads();
        }
        float chunkSuffExcl = scanF[tid] - fsum;
        #pragma unroll
        for (int q = 0; q < C; q++) bsum[base + q] = chunkSuffExcl + floc[q];
        __syncthreads();

        // 6) per-element: S_k = suffix beyond bucket + in-bucket correction (exact, tie-correct)
        for (int k = tid; k < N; k += T3) {
            if (k == row) continue;  // diagonal k dropped
            float v = d_row[k];
            int b = (int)(v * scale);
            b = min(max(b, 0), NB - 1);
            float S = bsum[b];
            int e0 = start[b], e1 = start[b + 1];
            for (int p = e0; p < e1; p++) {
                int j2 = sidx[p];
                if (d_row[j2] >= v) S += e_row[j2];
            }
            localSum += logf(S);
        }
    }

    red[tid] = localSum;
    __syncthreads();
    #pragma unroll
    for (int s = T3 / 2; s > 0; s >>= 1) {
        if (tid < s) red[tid] += red[tid + s];
        __syncthreads();
    }
    if (tid == 0) atomicAdd(&acc[1], (double)red[0]);
}

// ---------------- final: combine ----------------
__global__ void final_kernel(const double* __restrict__ acc, float* __restrict__ out) {
    double denom = (double)N * (double)(N - 1);
    out[0] = (float)(-(acc[0] - 0.5 * acc[1]) / denom);
}

extern "C" void kernel_launch(void* const* d_in, const int* in_sizes, int n_in,
                              void* d_out, int out_size, void* d_ws, size_t ws_size,
                              hipStream_t stream) {
    const float* theta = (const float*)d_in[0];
    const float* shift = (const float*)d_in[1];
    const float* feat  = (const float*)d_in[2];
    float* out = (float*)d_out;

    char* ws = (char*)d_ws;
    double* acc = (double*)(ws + WS_ACC_OFF);
    float* x2 = (float*)(ws + WS_X2_OFF);
    __hip_bfloat16* E = (__hip_bfloat16*)(ws + WS_E_OFF);

    hipMemsetAsync(acc, 0, 2 * sizeof(double), stream);
    x2_kernel<<<N, 64, 0, stream>>>(feat, x2);
    gram_kernel<<<dim3(64, 64), dim3(16, 16), 0, stream>>>(feat, x2, E, acc);
    lms_kernel<<<N, T3, 0, stream>>>(E, theta, shift, acc);
    final_kernel<<<1, 1, 0, stream>>>(acc, out);
}

// Round 2
// 420.470 us; speedup vs baseline: 1.9036x; 1.9036x over previous
//
#include <hip/hip_runtime.h>
#include <hip/hip_bf16.h>

#define N 4096
#define D 128
#define NB 1024          // buckets per row (avg ~4 elements/bucket)
#define T3 256           // threads for lms kernel
#define EPT (N / T3)     // 16 elements per thread
#define BPT (NB / T3)    // 4 buckets per thread

static constexpr size_t WS_ACC_OFF = 0;       // double acc[2]: {sum_logits, sum_lms}
static constexpr size_t WS_X2_OFF  = 64;      // float x2[N]
static constexpr size_t WS_E_OFF   = 32768;   // bf16 E[N*N] (33.5 MB)

// ---------------- kernel 1: row squared norms ----------------
__global__ void x2_kernel(const float* __restrict__ f, float* __restrict__ x2) {
    int row = blockIdx.x;
    int t = threadIdx.x;
    float a = f[row * D + t];
    float b = f[row * D + t + 64];
    float v = a * a + b * b;
    #pragma unroll
    for (int off = 32; off > 0; off >>= 1) v += __shfl_down(v, off);
    if (t == 0) x2[row] = v;
}

// ---------------- kernel 2: Gram -> e = exp(-dist/2) (bf16), sum logits ----------------
__global__ __launch_bounds__(256) void gram_kernel(const float* __restrict__ f,
                                                   const float* __restrict__ x2,
                                                   __hip_bfloat16* __restrict__ E,
                                                   double* __restrict__ acc) {
    __shared__ __align__(16) float As[64][68];
    __shared__ __align__(16) float Bs[64][68];
    __shared__ float red[256];

    int tx = threadIdx.x, ty = threadIdx.y;
    int tid = ty * 16 + tx;
    int rowBase = blockIdx.y * 64, colBase = blockIdx.x * 64;

    float accv[4][4];
    #pragma unroll
    for (int i = 0; i < 4; i++)
        #pragma unroll
        for (int j = 0; j < 4; j++) accv[i][j] = 0.f;

    for (int kc = 0; kc < D; kc += 64) {
        __syncthreads();
        #pragma unroll
        for (int it = 0; it < 4; it++) {
            int lin4 = tid + it * 256;
            int row = lin4 >> 4;
            int k4 = (lin4 & 15) * 4;
            float4 va = *(const float4*)&f[(size_t)(rowBase + row) * D + kc + k4];
            *(float4*)&As[row][k4] = va;
            float4 vb = *(const float4*)&f[(size_t)(colBase + row) * D + kc + k4];
            *(float4*)&Bs[row][k4] = vb;
        }
        __syncthreads();
        #pragma unroll
        for (int k = 0; k < 64; k += 4) {
            float4 a4[4], b4[4];
            #pragma unroll
            for (int i = 0; i < 4; i++) a4[i] = *(float4*)&As[ty + 16 * i][k];
            #pragma unroll
            for (int j = 0; j < 4; j++) b4[j] = *(float4*)&Bs[tx + 16 * j][k];
            #pragma unroll
            for (int i = 0; i < 4; i++)
                #pragma unroll
                for (int j = 0; j < 4; j++) {
                    accv[i][j] += a4[i].x * b4[j].x;
                    accv[i][j] += a4[i].y * b4[j].y;
                    accv[i][j] += a4[i].z * b4[j].z;
                    accv[i][j] += a4[i].w * b4[j].w;
                }
        }
    }

    float x2i[4], x2j[4];
    #pragma unroll
    for (int i = 0; i < 4; i++) x2i[i] = x2[rowBase + ty + 16 * i];
    #pragma unroll
    for (int j = 0; j < 4; j++) x2j[j] = x2[colBase + tx + 16 * j];

    float sumLogit = 0.f;
    #pragma unroll
    for (int i = 0; i < 4; i++) {
        #pragma unroll
        for (int j = 0; j < 4; j++) {
            int gi = rowBase + ty + 16 * i;
            int gj = colBase + tx + 16 * j;
            float sq = x2i[i] + x2j[j] - 2.f * accv[i][j];
            sq = fmaxf(sq, 0.f);
            float logit = (sq > 0.f) ? (-0.5f * sqrtf(sq)) : 0.f;
            float e = __expf(logit);
            if (gi == gj) { e = 0.f; logit = 0.f; }
            sumLogit += logit;
            E[(size_t)gi * N + gj] = __float2bfloat16(e);
        }
    }

    red[tid] = sumLogit;
    __syncthreads();
    #pragma unroll
    for (int s = 128; s > 0; s >>= 1) {
        if (tid < s) red[tid] += red[tid + s];
        __syncthreads();
    }
    if (tid == 0) atomicAdd(&acc[0], (double)red[0]);
}

// ---------------- kernel 3: per-(row,matrix) bucketed masked log-sum ----------------
// grid = (N, 2). Counting-sort by value into LDS, suffix-sum buckets, exact
// in-bucket tie-correct compare. All scans via wave shuffles (wave=64).
__global__ __launch_bounds__(T3, 4) void lms_kernel(const __hip_bfloat16* __restrict__ E,
                                                    const float* __restrict__ theta,
                                                    const float* __restrict__ shift,
                                                    double* __restrict__ acc) {
    __shared__ float d_sorted[N];            // 16 KB
    __shared__ unsigned short e_sorted[N];   // 8 KB (raw bf16 bits)
    __shared__ int cursor[NB];               // 4 KB: counts -> starts -> ends
    __shared__ float bsum[NB];               // 4 KB: suffix sums beyond bucket
    __shared__ int waveTotI[4];
    __shared__ float waveTotF[4];
    __shared__ float waveRed[4];

    int tid = threadIdx.x;
    int lane = tid & 63;
    int wave = tid >> 6;
    int row = blockIdx.x;
    const float* dmat = blockIdx.y ? shift : theta;
    float scale = blockIdx.y ? ((float)NB / 100.0f) : ((float)NB / 180.0f);

    // zero bucket counters
    #pragma unroll
    for (int q = 0; q < BPT; q++) cursor[tid + q * T3] = 0;

    // vectorized load of this thread's 16 d values + 16 e (bf16 bits)
    // element q: j = (q/4)*1024 + tid*4 + (q%4)
    float dc[EPT];
    uint2 ev[4];
    {
        const float4* drow4 = (const float4*)&dmat[(size_t)row * N];
        const uint2* erow2 = (const uint2*)&E[(size_t)row * N];
        #pragma unroll
        for (int c4 = 0; c4 < 4; c4++) {
            float4 v = drow4[c4 * 1024 / 4 + tid];
            dc[c4 * 4 + 0] = v.x; dc[c4 * 4 + 1] = v.y;
            dc[c4 * 4 + 2] = v.z; dc[c4 * 4 + 3] = v.w;
            ev[c4] = erow2[c4 * 256 + tid];
        }
    }
    __syncthreads();   // counters zeroed

    // 1) histogram
    #pragma unroll
    for (int q = 0; q < EPT; q++) {
        int b = (int)(dc[q] * scale);
        b = min(max(b, 0), NB - 1);
        atomicAdd(&cursor[b], 1);
    }
    __syncthreads();

    // 2) exclusive prefix scan of counts -> starts (in place), wave-shuffle based
    int base = tid * BPT;
    {
        int c[BPT];
        int t = 0;
        #pragma unroll
        for (int q = 0; q < BPT; q++) { c[q] = cursor[base + q]; t += c[q]; }
        int incl = t;
        #pragma unroll
        for (int off = 1; off < 64; off <<= 1) {
            int v = __shfl_up(incl, off);
            if (lane >= off) incl += v;
        }
        if (lane == 63) waveTotI[wave] = incl;
        __syncthreads();
        int before = 0;
        for (int w = 0; w < wave; w++) before += waveTotI[w];
        int run = before + incl - t;   // exclusive start of this thread's bucket range
        #pragma unroll
        for (int q = 0; q < BPT; q++) { cursor[base + q] = run; run += c[q]; }
    }
    __syncthreads();

    // 3) scatter values (counting sort by value)
    #pragma unroll
    for (int q = 0; q < EPT; q++) {
        int b = (int)(dc[q] * scale);
        b = min(max(b, 0), NB - 1);
        int pos = atomicAdd(&cursor[b], 1);
        int c4 = q >> 2, idx = q & 3;
        unsigned u = (idx < 2) ? ev[c4].x : ev[c4].y;
        unsigned short es = (idx & 1) ? (unsigned short)(u >> 16) : (unsigned short)(u & 0xffff);
        d_sorted[pos] = dc[q];
        e_sorted[pos] = es;
    }
    __syncthreads();
    // now cursor[b] = end[b]; start[b] = cursor[b-1] (or 0)

    // 4) per-bucket e sums (regs) + wave-shuffle suffix scan -> bsum[b] = sum beyond bucket b
    {
        float s[BPT];
        float t = 0.f;
        int s0 = base ? cursor[base - 1] : 0;
        #pragma unroll
        for (int q = 0; q < BPT; q++) {
            int e1 = cursor[base + q];
            float ss = 0.f;
            for (int p = s0; p < e1; p++)
                ss += __uint_as_float(((unsigned)e_sorted[p]) << 16);
            s[q] = ss; t += ss; s0 = e1;
        }
        float incl = t;   // will become sum over threads >= lane in wave
        #pragma unroll
        for (int off = 1; off < 64; off <<= 1) {
            float v = __shfl_down(incl, off);
            if (lane + off < 64) incl += v;
        }
        if (lane == 0) waveTotF[wave] = incl;
        __syncthreads();
        float beyond = 0.f;
        for (int w = wave + 1; w < 4; w++) beyond += waveTotF[w];
        float run = beyond + incl - t;   // sum over all buckets after this thread's range
        #pragma unroll
        for (int q = BPT - 1; q >= 0; q--) { bsum[base + q] = run; run += s[q]; }
    }
    __syncthreads();

    // 5) per-element: S_k = bsum[b] + exact in-bucket [d_j >= d_k] sum; accumulate log
    float localSum = 0.f;
    #pragma unroll
    for (int q = 0; q < EPT; q++) {
        int j = (q >> 2) * 1024 + tid * 4 + (q & 3);
        if (j == row) continue;          // diagonal k dropped
        float v = dc[q];
        int b = (int)(v * scale);
        b = min(max(b, 0), NB - 1);
        float S = bsum[b];
        int s0 = b ? cursor[b - 1] : 0;
        int e1 = cursor[b];
        for (int p = s0; p < e1; p++)
            if (d_sorted[p] >= v)
                S += __uint_as_float(((unsigned)e_sorted[p]) << 16);
        localSum += __logf(S);
    }

    // block reduce + global atomic
    #pragma unroll
    for (int off = 32; off > 0; off >>= 1) localSum += __shfl_down(localSum, off);
    if (lane == 0) waveRed[wave] = localSum;
    __syncthreads();
    if (tid == 0) {
        float s4 = waveRed[0] + waveRed[1] + waveRed[2] + waveRed[3];
        atomicAdd(&acc[1], (double)s4);
    }
}

// ---------------- final: combine ----------------
__global__ void final_kernel(const double* __restrict__ acc, float* __restrict__ out) {
    double denom = (double)N * (double)(N - 1);
    out[0] = (float)(-(acc[0] - 0.5 * acc[1]) / denom);
}

extern "C" void kernel_launch(void* const* d_in, const int* in_sizes, int n_in,
                              void* d_out, int out_size, void* d_ws, size_t ws_size,
                              hipStream_t stream) {
    const float* theta = (const float*)d_in[0];
    const float* shift = (const float*)d_in[1];
    const float* feat  = (const float*)d_in[2];
    float* out = (float*)d_out;

    char* ws = (char*)d_ws;
    double* acc = (double*)(ws + WS_ACC_OFF);
    float* x2 = (float*)(ws + WS_X2_OFF);
    __hip_bfloat16* E = (__hip_bfloat16*)(ws + WS_E_OFF);

    hipMemsetAsync(acc, 0, 2 * sizeof(double), stream);
    x2_kernel<<<N, 64, 0, stream>>>(feat, x2);
    gram_kernel<<<dim3(64, 64), dim3(16, 16), 0, stream>>>(feat, x2, E, acc);
    lms_kernel<<<dim3(N, 2), T3, 0, stream>>>(E, theta, shift, acc);
    final_kernel<<<1, 1, 0, stream>>>(acc, out);
}

// Round 3
// 348.278 us; speedup vs baseline: 2.2982x; 1.2073x over previous
//
#include <hip/hip_runtime.h>
#include <hip/hip_bf16.h>

#define N 4096
#define D 128
#define NB 1024          // buckets (= dkey >> 6), avg ~4 elements/bucket
#define T3 256           // threads for lms kernel
#define EPT (N / T3)     // 16 elements per thread
#define BPT (NB / T3)    // 4 buckets per thread

static constexpr size_t WS_ACC_OFF = 0;       // double acc[2]: {sum_logits, sum_lms}
static constexpr size_t WS_X2_OFF  = 64;      // float x2[N]
static constexpr size_t WS_E_OFF   = 32768;   // bf16 E[N*N] (33.5 MB)

// ---------------- kernel 1: row squared norms ----------------
__global__ void x2_kernel(const float* __restrict__ f, float* __restrict__ x2) {
    int row = blockIdx.x;
    int t = threadIdx.x;
    float a = f[row * D + t];
    float b = f[row * D + t + 64];
    float v = a * a + b * b;
    #pragma unroll
    for (int off = 32; off > 0; off >>= 1) v += __shfl_down(v, off);
    if (t == 0) x2[row] = v;
}

// ---------------- kernel 2: Gram -> e = exp(-dist/2) (bf16), sum logits ----------------
// 128x128 block tile, 8x8 micro-tile per thread (16 FMA per ds_read_b128).
__global__ __launch_bounds__(256, 3) void gram_kernel(const float* __restrict__ f,
                                                      const float* __restrict__ x2,
                                                      __hip_bfloat16* __restrict__ E,
                                                      double* __restrict__ acc) {
    __shared__ __align__(16) float As[128][36];  // pad 36: %32==4 -> A broadcast, B 2-way (free)
    __shared__ __align__(16) float Bs[128][36];
    __shared__ float red[256];

    int tid = threadIdx.x;
    int tx = tid & 15, ty = tid >> 4;
    int rowBase = blockIdx.y * 128, colBase = blockIdx.x * 128;

    float accv[8][8];
    #pragma unroll
    for (int i = 0; i < 8; i++)
        #pragma unroll
        for (int j = 0; j < 8; j++) accv[i][j] = 0.f;

    for (int kc = 0; kc < D; kc += 32) {
        __syncthreads();
        #pragma unroll
        for (int it = 0; it < 4; it++) {
            int lin = tid + it * 256;        // 1024 float4 per 128x32 tile
            int row = lin >> 3;              // 8 float4 per row
            int c4 = (lin & 7) * 4;
            *(float4*)&As[row][c4] = *(const float4*)&f[(size_t)(rowBase + row) * D + kc + c4];
            *(float4*)&Bs[row][c4] = *(const float4*)&f[(size_t)(colBase + row) * D + kc + c4];
        }
        __syncthreads();
        #pragma unroll
        for (int k4 = 0; k4 < 32; k4 += 4) {
            float4 a4[8];
            #pragma unroll
            for (int i = 0; i < 8; i++) a4[i] = *(float4*)&As[ty + 16 * i][k4];
            #pragma unroll
            for (int jh = 0; jh < 2; jh++) {
                float4 b4[4];
                #pragma unroll
                for (int j = 0; j < 4; j++) b4[j] = *(float4*)&Bs[tx + 16 * (jh * 4 + j)][k4];
                #pragma unroll
                for (int i = 0; i < 8; i++)
                    #pragma unroll
                    for (int j = 0; j < 4; j++) {
                        float s = accv[i][jh * 4 + j];
                        s += a4[i].x * b4[j].x;
                        s += a4[i].y * b4[j].y;
                        s += a4[i].z * b4[j].z;
                        s += a4[i].w * b4[j].w;
                        accv[i][jh * 4 + j] = s;
                    }
            }
        }
    }

    float x2i[8], x2j[8];
    #pragma unroll
    for (int i = 0; i < 8; i++) x2i[i] = x2[rowBase + ty + 16 * i];
    #pragma unroll
    for (int j = 0; j < 8; j++) x2j[j] = x2[colBase + tx + 16 * j];

    float sumLogit = 0.f;
    #pragma unroll
    for (int i = 0; i < 8; i++) {
        int gi = rowBase + ty + 16 * i;
        #pragma unroll
        for (int j = 0; j < 8; j++) {
            int gj = colBase + tx + 16 * j;
            float sq = x2i[i] + x2j[j] - 2.f * accv[i][j];
            sq = fmaxf(sq, 0.f);
            float logit = (sq > 0.f) ? (-0.5f * sqrtf(sq)) : 0.f;
            float e = __expf(logit);
            if (gi == gj) { e = 0.f; logit = 0.f; }
            sumLogit += logit;
            E[(size_t)gi * N + gj] = __float2bfloat16(e);
        }
    }

    red[tid] = sumLogit;
    __syncthreads();
    #pragma unroll
    for (int s = 128; s > 0; s >>= 1) {
        if (tid < s) red[tid] += red[tid + s];
        __syncthreads();
    }
    if (tid == 0) atomicAdd(&acc[0], (double)red[0]);
}

// ---------------- kernel 3: per-(row,matrix) bucketed masked log-sum ----------------
// grid = (N, 2). Key idea: pack (16-bit monotone d-key | bf16 e-bits) into ONE u32;
// counting-sort packed values into LDS, suffix-sum buckets, masked-compare in-bucket.
// One b32 LDS access per probe; 24.6 KB LDS -> 6 blocks/CU.
__global__ __launch_bounds__(T3, 6) void lms_kernel(const __hip_bfloat16* __restrict__ E,
                                                    const float* __restrict__ theta,
                                                    const float* __restrict__ shift,
                                                    double* __restrict__ acc) {
    __shared__ unsigned pk_sorted[N];        // 16 KB
    __shared__ int cursor[NB];               // 4 KB: counts -> starts -> ends
    __shared__ float bsum[NB];               // 4 KB: suffix sums beyond bucket
    __shared__ int waveTotI[4];
    __shared__ float waveTotF[4];
    __shared__ float waveRed[4];

    int tid = threadIdx.x;
    int lane = tid & 63;
    int wave = tid >> 6;
    int row = blockIdx.x;
    const float* dmat = blockIdx.y ? shift : theta;
    float kscale = blockIdx.y ? (65536.0f / 100.0f) : (65536.0f / 180.0f);

    // zero bucket counters
    #pragma unroll
    for (int q = 0; q < BPT; q++) cursor[tid + q * T3] = 0;

    // load 16 d + 16 e per thread (element q: j = (q/4)*1024 + tid*4 + (q%4)),
    // pack into u32 keys: (dkey16 << 16) | e_bf16_bits
    unsigned pk[EPT];
    {
        const float4* drow4 = (const float4*)&dmat[(size_t)row * N];
        const uint2* erow2 = (const uint2*)&E[(size_t)row * N];
        #pragma unroll
        for (int c4 = 0; c4 < 4; c4++) {
            float4 v = drow4[c4 * 256 + tid];
            uint2 e2 = erow2[c4 * 256 + tid];
            float dv[4] = {v.x, v.y, v.z, v.w};
            unsigned eb[4] = {e2.x & 0xffffu, e2.x >> 16, e2.y & 0xffffu, e2.y >> 16};
            #pragma unroll
            for (int idx = 0; idx < 4; idx++) {
                int dk = (int)(dv[idx] * kscale);
                dk = min(max(dk, 0), 65535);
                pk[c4 * 4 + idx] = ((unsigned)dk << 16) | eb[idx];
            }
        }
    }
    __syncthreads();   // counters zeroed

    // 1) histogram (bucket = dkey >> 6 = pk >> 22)
    #pragma unroll
    for (int q = 0; q < EPT; q++)
        atomicAdd(&cursor[pk[q] >> 22], 1);
    __syncthreads();

    // 2) exclusive prefix scan of counts -> starts (in place), wave-shuffle based
    int base = tid * BPT;
    {
        int c[BPT];
        int t = 0;
        #pragma unroll
        for (int q = 0; q < BPT; q++) { c[q] = cursor[base + q]; t += c[q]; }
        int incl = t;
        #pragma unroll
        for (int off = 1; off < 64; off <<= 1) {
            int v = __shfl_up(incl, off);
            if (lane >= off) incl += v;
        }
        if (lane == 63) waveTotI[wave] = incl;
        __syncthreads();
        int before = 0;
        for (int w = 0; w < wave; w++) before += waveTotI[w];
        int run = before + incl - t;
        #pragma unroll
        for (int q = 0; q < BPT; q++) { cursor[base + q] = run; run += c[q]; }
    }
    __syncthreads();

    // 3) scatter packed values (counting sort)
    #pragma unroll
    for (int q = 0; q < EPT; q++) {
        int pos = atomicAdd(&cursor[pk[q] >> 22], 1);
        pk_sorted[pos] = pk[q];
    }
    __syncthreads();
    // now cursor[b] = end[b]; start[b] = cursor[b-1] (or 0)

    // 4) per-bucket e sums + wave-shuffle suffix scan -> bsum[b] = sum beyond bucket b
    {
        float s[BPT];
        float t = 0.f;
        int s0 = base ? cursor[base - 1] : 0;
        #pragma unroll
        for (int q = 0; q < BPT; q++) {
            int e1 = cursor[base + q];
            float ss = 0.f;
            for (int p = s0; p < e1; p++)
                ss += __uint_as_float(pk_sorted[p] << 16);
            s[q] = ss; t += ss; s0 = e1;
        }
        float incl = t;
        #pragma unroll
        for (int off = 1; off < 64; off <<= 1) {
            float v = __shfl_down(incl, off);
            if (lane + off < 64) incl += v;
        }
        if (lane == 0) waveTotF[wave] = incl;
        __syncthreads();
        float beyond = 0.f;
        for (int w = wave + 1; w < 4; w++) beyond += waveTotF[w];
        float run = beyond + incl - t;
        #pragma unroll
        for (int q = BPT - 1; q >= 0; q--) { bsum[base + q] = run; run += s[q]; }
    }
    __syncthreads();

    // 5) per-element: S_k = bsum[b] + masked in-bucket sum; accumulate log
    float localSum = 0.f;
    #pragma unroll
    for (int q = 0; q < EPT; q++) {
        int j = (q >> 2) * 1024 + tid * 4 + (q & 3);
        if (j == row) continue;          // diagonal k dropped
        unsigned vk = pk[q] & 0xffff0000u;
        int b = pk[q] >> 22;
        float S = bsum[b];
        int s0 = b ? cursor[b - 1] : 0;
        int e1 = cursor[b];
        for (int p = s0; p < e1; p++) {
            unsigned u = pk_sorted[p];
            if ((u & 0xffff0000u) >= vk)
                S += __uint_as_float(u << 16);
        }
        localSum += __logf(S);
    }

    // block reduce + global atomic
    #pragma unroll
    for (int off = 32; off > 0; off >>= 1) localSum += __shfl_down(localSum, off);
    if (lane == 0) waveRed[wave] = localSum;
    __syncthreads();
    if (tid == 0) {
        float s4 = waveRed[0] + waveRed[1] + waveRed[2] + waveRed[3];
        atomicAdd(&acc[1], (double)s4);
    }
}

// ---------------- final: combine ----------------
__global__ void final_kernel(const double* __restrict__ acc, float* __restrict__ out) {
    double denom = (double)N * (double)(N - 1);
    out[0] = (float)(-(acc[0] - 0.5 * acc[1]) / denom);
}

extern "C" void kernel_launch(void* const* d_in, const int* in_sizes, int n_in,
                              void* d_out, int out_size, void* d_ws, size_t ws_size,
                              hipStream_t stream) {
    const float* theta = (const float*)d_in[0];
    const float* shift = (const float*)d_in[1];
    const float* feat  = (const float*)d_in[2];
    float* out = (float*)d_out;

    char* ws = (char*)d_ws;
    double* acc = (double*)(ws + WS_ACC_OFF);
    float* x2 = (float*)(ws + WS_X2_OFF);
    __hip_bfloat16* E = (__hip_bfloat16*)(ws + WS_E_OFF);

    hipMemsetAsync(acc, 0, 2 * sizeof(double), stream);
    x2_kernel<<<N, 64, 0, stream>>>(feat, x2);
    gram_kernel<<<dim3(32, 32), 256, 0, stream>>>(feat, x2, E, acc);
    lms_kernel<<<dim3(N, 2), T3, 0, stream>>>(E, theta, shift, acc);
    final_kernel<<<1, 1, 0, stream>>>(acc, out);
}

// Round 4
// 336.025 us; speedup vs baseline: 2.3820x; 1.0365x over previous
//
#include <hip/hip_runtime.h>
#include <hip/hip_bf16.h>

#define N 4096
#define D 128
#define NB2 4096         // bins for lms (12-bit key; bin == key)
#define T3 256           // threads for lms kernel
#define EPT (N / T3)     // 16 elements per thread
#define BPT2 (NB2 / T3)  // 16 bins per thread

static constexpr size_t WS_ACC_OFF = 0;       // double acc[2]: {sum_logits, sum_lms}
static constexpr size_t WS_X2_OFF  = 64;      // float x2[N]
static constexpr size_t WS_E_OFF   = 32768;   // bf16 E[N*N] (33.5 MB)

typedef __attribute__((ext_vector_type(8))) short short8;   // 8 bf16 (4 VGPRs)
typedef __attribute__((ext_vector_type(4))) float f32x4;    // MFMA C/D

__device__ inline unsigned short f2bf(float x) {
    __hip_bfloat16 h = __float2bfloat16(x);
    return *(unsigned short*)&h;
}

// ---------------- kernel 1: row squared norms (fp32 exact) ----------------
__global__ void x2_kernel(const float* __restrict__ f, float* __restrict__ x2) {
    int row = blockIdx.x;
    int t = threadIdx.x;
    float a = f[row * D + t];
    float b = f[row * D + t + 64];
    float v = a * a + b * b;
    #pragma unroll
    for (int off = 32; off > 0; off >>= 1) v += __shfl_down(v, off);
    if (t == 0) x2[row] = v;
}

// ---------------- kernel 2: Gram via bf16 MFMA -> e = exp(-dist/2) (bf16) ----------------
// 128x128 tile per block, 4 waves, each wave 64x64 via 4x4 tiles of 16x16x32 MFMA.
// K staged in 2 chunks of 64 (LDS 36.9 KB). Gram symmetry makes the kernel
// immune to A/B-role / C-transpose layout mistakes.
__global__ __launch_bounds__(256, 3) void gram_kernel(const float* __restrict__ f,
                                                      const float* __restrict__ x2,
                                                      __hip_bfloat16* __restrict__ E,
                                                      double* __restrict__ acc) {
    __shared__ __align__(16) unsigned short As[128 * 72];  // 64 k + 8 pad per row
    __shared__ __align__(16) unsigned short Bs[128 * 72];
    __shared__ float waveRed[4];

    int tid = threadIdx.x;
    int lane = tid & 63;
    int wave = tid >> 6;
    int wr = wave >> 1, wc = wave & 1;           // 64x64 quadrant of the 128x128 tile
    int rowBase = blockIdx.y * 128, colBase = blockIdx.x * 128;

    f32x4 accv[4][4];
    #pragma unroll
    for (int i = 0; i < 4; i++)
        #pragma unroll
        for (int j = 0; j < 4; j++) accv[i][j] = (f32x4){0.f, 0.f, 0.f, 0.f};

    int col = lane & 15;       // C/D col, and frag row selector
    int quad = lane >> 4;      // C/D row quad, and frag k-group

    for (int kc = 0; kc < D; kc += 64) {
        __syncthreads();
        // stage 128x64 fp32 -> bf16 for both panels
        #pragma unroll
        for (int it = 0; it < 8; it++) {
            int lin = tid + it * 256;            // 2048 float4 per panel
            int m = lin >> 4;                    // 16 float4 per row
            int f4i = lin & 15;
            float4 va = ((const float4*)f)[(size_t)(rowBase + m) * 32 + (kc >> 2) + f4i];
            float4 vb = ((const float4*)f)[(size_t)(colBase + m) * 32 + (kc >> 2) + f4i];
            ushort4 ua = {f2bf(va.x), f2bf(va.y), f2bf(va.z), f2bf(va.w)};
            ushort4 ub = {f2bf(vb.x), f2bf(vb.y), f2bf(vb.z), f2bf(vb.w)};
            *(ushort4*)&As[m * 72 + f4i * 4] = ua;
            *(ushort4*)&Bs[m * 72 + f4i * 4] = ub;
        }
        __syncthreads();

        #pragma unroll
        for (int c = 0; c < 2; c++) {            // two k-chunks of 32
            int k = c * 32 + quad * 8;
            short8 af[4], bf[4];
            #pragma unroll
            for (int i = 0; i < 4; i++)
                af[i] = *(const short8*)&As[(wr * 64 + i * 16 + col) * 72 + k];
            #pragma unroll
            for (int j = 0; j < 4; j++)
                bf[j] = *(const short8*)&Bs[(wc * 64 + j * 16 + col) * 72 + k];
            #pragma unroll
            for (int i = 0; i < 4; i++)
                #pragma unroll
                for (int j = 0; j < 4; j++)
                    accv[i][j] = __builtin_amdgcn_mfma_f32_16x16x32_bf16(
                        af[i], bf[j], accv[i][j], 0, 0, 0);
        }
    }

    // epilogue: sq -> logit -> e(bf16) -> store; accumulate sum of logits
    float x2j[4];
    #pragma unroll
    for (int j = 0; j < 4; j++) x2j[j] = x2[colBase + wc * 64 + j * 16 + col];

    float sumLogit = 0.f;
    #pragma unroll
    for (int i = 0; i < 4; i++) {
        #pragma unroll
        for (int r = 0; r < 4; r++) {
            int gi = rowBase + wr * 64 + i * 16 + quad * 4 + r;
            float x2i = x2[gi];
            #pragma unroll
            for (int j = 0; j < 4; j++) {
                int gj = colBase + wc * 64 + j * 16 + col;
                float sq = x2i + x2j[j] - 2.f * accv[i][j][r];
                sq = fmaxf(sq, 0.f);
                float logit = (sq > 0.f) ? (-0.5f * sqrtf(sq)) : 0.f;
                float e = __expf(logit);
                if (gi == gj) { e = 0.f; logit = 0.f; }
                sumLogit += logit;
                E[(size_t)gi * N + gj] = __float2bfloat16(e);
            }
        }
    }

    #pragma unroll
    for (int off = 32; off > 0; off >>= 1) sumLogit += __shfl_down(sumLogit, off);
    if (lane == 0) waveRed[wave] = sumLogit;
    __syncthreads();
    if (tid == 0)
        atomicAdd(&acc[0], (double)(waveRed[0] + waveRed[1] + waveRed[2] + waveRed[3]));
}

// ---------------- kernel 3: per-(row,matrix) histogram-suffix masked log-sum ----------------
// grid = (N, 2). 12-bit monotone key; bin == key. Histogram e-sums directly
// (float LDS atomics), inclusive suffix scan over 4096 bins, then
// S_k = hsum[key_k] with ONE LDS read. No sorting, no divergent probe loops.
__global__ __launch_bounds__(T3, 6) void lms_kernel(const __hip_bfloat16* __restrict__ E,
                                                    const float* __restrict__ theta,
                                                    const float* __restrict__ shift,
                                                    double* __restrict__ acc) {
    __shared__ __align__(16) float hsum[NB2];   // 16 KB
    __shared__ float waveTot[4];
    __shared__ float waveRed[4];

    int tid = threadIdx.x;
    int lane = tid & 63;
    int wave = tid >> 6;
    int row = blockIdx.x;
    const float* dmat = blockIdx.y ? shift : theta;
    float kscale = blockIdx.y ? ((float)NB2 / 100.0f) : ((float)NB2 / 180.0f);

    // zero bins
    #pragma unroll
    for (int q = 0; q < BPT2; q++) hsum[tid + q * T3] = 0.f;

    // load 16 d + 16 e per thread; pack (key12 << 16) | e_bf16_bits
    unsigned pk[EPT];
    {
        const float4* drow4 = (const float4*)&dmat[(size_t)row * N];
        const uint2* erow2 = (const uint2*)&E[(size_t)row * N];
        #pragma unroll
        for (int c4 = 0; c4 < 4; c4++) {
            float4 v = drow4[c4 * 256 + tid];
            uint2 e2 = erow2[c4 * 256 + tid];
            float dv[4] = {v.x, v.y, v.z, v.w};
            unsigned eb[4] = {e2.x & 0xffffu, e2.x >> 16, e2.y & 0xffffu, e2.y >> 16};
            #pragma unroll
            for (int idx = 0; idx < 4; idx++) {
                int dk = (int)(dv[idx] * kscale);
                dk = min(max(dk, 0), NB2 - 1);
                pk[c4 * 4 + idx] = ((unsigned)dk << 16) | eb[idx];
            }
        }
    }
    __syncthreads();   // bins zeroed

    // 1) histogram e-sums directly (diagonal e == 0, contributes nothing)
    #pragma unroll
    for (int q = 0; q < EPT; q++)
        atomicAdd(&hsum[pk[q] >> 16], __uint_as_float(pk[q] << 16));
    __syncthreads();

    // 2) inclusive suffix scan over 4096 bins (16 contiguous per thread)
    int base = tid * BPT2;
    {
        float s[BPT2];
        #pragma unroll
        for (int u = 0; u < 4; u++)
            *(float4*)&s[u * 4] = *(const float4*)&hsum[base + u * 4];
        float t = 0.f;
        #pragma unroll
        for (int q = BPT2 - 1; q >= 0; q--) { t += s[q]; s[q] = t; }  // in-thread inclusive suffix
        float incl = t;
        #pragma unroll
        for (int off = 1; off < 64; off <<= 1) {
            float v = __shfl_down(incl, off);
            if (lane + off < 64) incl += v;
        }
        if (lane == 0) waveTot[wave] = incl;
        __syncthreads();
        float beyond = 0.f;
        for (int w = wave + 1; w < 4; w++) beyond += waveTot[w];
        float add = beyond + (incl - t);   // sum over all bins after this thread's range
        #pragma unroll
        for (int q = 0; q < BPT2; q++) s[q] += add;
        #pragma unroll
        for (int u = 0; u < 4; u++)
            *(float4*)&hsum[base + u * 4] = *(const float4*)&s[u * 4];
    }
    __syncthreads();

    // 3) per-element: S_k = hsum[key_k]; accumulate log
    float localSum = 0.f;
    #pragma unroll
    for (int q = 0; q < EPT; q++) {
        int j = (q >> 2) * 1024 + tid * 4 + (q & 3);
        if (j == row) continue;          // diagonal k dropped
        localSum += __logf(hsum[pk[q] >> 16]);
    }

    #pragma unroll
    for (int off = 32; off > 0; off >>= 1) localSum += __shfl_down(localSum, off);
    if (lane == 0) waveRed[wave] = localSum;
    __syncthreads();
    if (tid == 0)
        atomicAdd(&acc[1], (double)(waveRed[0] + waveRed[1] + waveRed[2] + waveRed[3]));
}

// ---------------- final: combine ----------------
__global__ void final_kernel(const double* __restrict__ acc, float* __restrict__ out) {
    double denom = (double)N * (double)(N - 1);
    out[0] = (float)(-(acc[0] - 0.5 * acc[1]) / denom);
}

extern "C" void kernel_launch(void* const* d_in, const int* in_sizes, int n_in,
                              void* d_out, int out_size, void* d_ws, size_t ws_size,
                              hipStream_t stream) {
    const float* theta = (const float*)d_in[0];
    const float* shift = (const float*)d_in[1];
    const float* feat  = (const float*)d_in[2];
    float* out = (float*)d_out;

    char* ws = (char*)d_ws;
    double* acc = (double*)(ws + WS_ACC_OFF);
    float* x2 = (float*)(ws + WS_X2_OFF);
    __hip_bfloat16* E = (__hip_bfloat16*)(ws + WS_E_OFF);

    hipMemsetAsync(acc, 0, 2 * sizeof(double), stream);
    x2_kernel<<<N, 64, 0, stream>>>(feat, x2);
    gram_kernel<<<dim3(32, 32), 256, 0, stream>>>(feat, x2, E, acc);
    lms_kernel<<<dim3(N, 2), T3, 0, stream>>>(E, theta, shift, acc);
    final_kernel<<<1, 1, 0, stream>>>(acc, out);
}

// Round 5
// 247.180 us; speedup vs baseline: 3.2381x; 1.3594x over previous
//
#include <hip/hip_runtime.h>
#include <hip/hip_bf16.h>

#define N 4096
#define D 128
#define NB2 4096         // bins for lms (12-bit key; bin == key)
#define T3 256           // threads for lms kernel
#define EPT (N / T3)     // 16 elements per thread
#define BPT2 (NB2 / T3)  // 16 bins per thread

#define ESCALE 33554432.0f          // 2^25 fixed-point scale for e-histogram
#define EINV   (1.0f / 33554432.0f)

static constexpr size_t WS_ACC_OFF = 0;       // double acc[2]: {sum_logits, sum_lms}
static constexpr size_t WS_X2_OFF  = 64;      // float x2[N]
static constexpr size_t WS_E_OFF   = 32768;   // bf16 E[N*N] (33.5 MB)

typedef __attribute__((ext_vector_type(8))) short short8;   // 8 bf16 (4 VGPRs)
typedef __attribute__((ext_vector_type(4))) float f32x4;    // MFMA C/D

__device__ inline unsigned short f2bf(float x) {
    __hip_bfloat16 h = __float2bfloat16(x);
    return *(unsigned short*)&h;
}

// ---------------- kernel 1: row squared norms (fp32 exact) ----------------
__global__ void x2_kernel(const float* __restrict__ f, float* __restrict__ x2) {
    int row = blockIdx.x;
    int t = threadIdx.x;
    float a = f[row * D + t];
    float b = f[row * D + t + 64];
    float v = a * a + b * b;
    #pragma unroll
    for (int off = 32; off > 0; off >>= 1) v += __shfl_down(v, off);
    if (t == 0) x2[row] = v;
}

// ---------------- kernel 2: Gram via bf16 MFMA -> e = exp(-dist/2) (bf16) ----------------
// 128x128 tile per block, 4 waves, each wave 64x64 via 4x4 tiles of 16x16x32 MFMA.
// Epilogue stages the bf16 tile through LDS (reusing As/Bs space) so E stores
// are coalesced dwordx4 (1 KB/wave-inst) instead of scattered 2-byte stores.
__global__ __launch_bounds__(256, 3) void gram_kernel(const float* __restrict__ f,
                                                      const float* __restrict__ x2,
                                                      __hip_bfloat16* __restrict__ E,
                                                      double* __restrict__ acc) {
    // As: [128][72] shorts, Bs: [128][72] shorts; reused as Ctile [128][136] shorts
    __shared__ __align__(16) unsigned short smem[2 * 128 * 72];
    __shared__ float waveRed[4];
    unsigned short* As = smem;
    unsigned short* Bs = smem + 128 * 72;

    int tid = threadIdx.x;
    int lane = tid & 63;
    int wave = tid >> 6;
    int wr = wave >> 1, wc = wave & 1;           // 64x64 quadrant of the 128x128 tile
    int rowBase = blockIdx.y * 128, colBase = blockIdx.x * 128;

    f32x4 accv[4][4];
    #pragma unroll
    for (int i = 0; i < 4; i++)
        #pragma unroll
        for (int j = 0; j < 4; j++) accv[i][j] = (f32x4){0.f, 0.f, 0.f, 0.f};

    int col = lane & 15;       // C/D col, and frag row selector
    int quad = lane >> 4;      // C/D row quad, and frag k-group

    for (int kc = 0; kc < D; kc += 64) {
        __syncthreads();
        // stage 128x64 fp32 -> bf16 for both panels
        #pragma unroll
        for (int it = 0; it < 8; it++) {
            int lin = tid + it * 256;            // 2048 float4 per panel
            int m = lin >> 4;                    // 16 float4 per row
            int f4i = lin & 15;
            float4 va = ((const float4*)f)[(size_t)(rowBase + m) * 32 + (kc >> 2) + f4i];
            float4 vb = ((const float4*)f)[(size_t)(colBase + m) * 32 + (kc >> 2) + f4i];
            ushort4 ua = {f2bf(va.x), f2bf(va.y), f2bf(va.z), f2bf(va.w)};
            ushort4 ub = {f2bf(vb.x), f2bf(vb.y), f2bf(vb.z), f2bf(vb.w)};
            *(ushort4*)&As[m * 72 + f4i * 4] = ua;
            *(ushort4*)&Bs[m * 72 + f4i * 4] = ub;
        }
        __syncthreads();

        #pragma unroll
        for (int c = 0; c < 2; c++) {            // two k-chunks of 32
            int k = c * 32 + quad * 8;
            short8 af[4], bf[4];
            #pragma unroll
            for (int i = 0; i < 4; i++)
                af[i] = *(const short8*)&As[(wr * 64 + i * 16 + col) * 72 + k];
            #pragma unroll
            for (int j = 0; j < 4; j++)
                bf[j] = *(const short8*)&Bs[(wc * 64 + j * 16 + col) * 72 + k];
            #pragma unroll
            for (int i = 0; i < 4; i++)
                #pragma unroll
                for (int j = 0; j < 4; j++)
                    accv[i][j] = __builtin_amdgcn_mfma_f32_16x16x32_bf16(
                        af[i], bf[j], accv[i][j], 0, 0, 0);
        }
    }

    // epilogue: sq -> logit -> e(bf16) -> LDS tile; accumulate sum of logits
    float x2j[4];
    #pragma unroll
    for (int j = 0; j < 4; j++) x2j[j] = x2[colBase + wc * 64 + j * 16 + col];

    __syncthreads();   // all waves done reading As/Bs; reuse as Ctile[128][136]

    float sumLogit = 0.f;
    #pragma unroll
    for (int i = 0; i < 4; i++) {
        #pragma unroll
        for (int r = 0; r < 4; r++) {
            int lr = wr * 64 + i * 16 + quad * 4 + r;
            int gi = rowBase + lr;
            float x2i = x2[gi];
            #pragma unroll
            for (int j = 0; j < 4; j++) {
                int lc = wc * 64 + j * 16 + col;
                int gj = colBase + lc;
                float sq = x2i + x2j[j] - 2.f * accv[i][j][r];
                sq = fmaxf(sq, 0.f);
                float logit = (sq > 0.f) ? (-0.5f * sqrtf(sq)) : 0.f;
                float e = __expf(logit);
                if (gi == gj) { e = 0.f; logit = 0.f; }
                sumLogit += logit;
                smem[lr * 136 + lc] = f2bf(e);
            }
        }
    }
    __syncthreads();

    // coalesced store: 128x128 bf16 tile, 16 B per lane
    #pragma unroll
    for (int it = 0; it < 8; it++) {
        int lin = tid + it * 256;        // 2048 chunks of 8 shorts
        int r = lin >> 4;
        int c8 = lin & 15;
        uint4 v = *(const uint4*)&smem[r * 136 + c8 * 8];   // 136*2B = 272B row, 16B-aligned
        *(uint4*)&E[(size_t)(rowBase + r) * N + colBase + c8 * 8] = v;
    }

    #pragma unroll
    for (int off = 32; off > 0; off >>= 1) sumLogit += __shfl_down(sumLogit, off);
    if (lane == 0) waveRed[wave] = sumLogit;
    __syncthreads();
    if (tid == 0)
        atomicAdd(&acc[0], (double)(waveRed[0] + waveRed[1] + waveRed[2] + waveRed[3]));
}

// ---------------- kernel 3: per-(row,matrix) histogram-suffix masked log-sum ----------------
// grid = (N, 2). 12-bit monotone key; bin == key. Histogram e-sums in 2^25
// fixed point via NATIVE ds_add_u32 (fp LDS atomicAdd is a CAS loop -> R4 regression),
// inclusive suffix scan over 4096 bins in float, then S_k = hsum[key_k].
__global__ __launch_bounds__(T3, 8) void lms_kernel(const __hip_bfloat16* __restrict__ E,
                                                    const float* __restrict__ theta,
                                                    const float* __restrict__ shift,
                                                    double* __restrict__ acc) {
    __shared__ __align__(16) unsigned histu[NB2];   // 16 KB; floats after scan
    __shared__ float waveTot[4];
    __shared__ float waveRed[4];
    float* histf = (float*)histu;

    int tid = threadIdx.x;
    int lane = tid & 63;
    int wave = tid >> 6;
    int row = blockIdx.x;
    const float* dmat = blockIdx.y ? shift : theta;
    float kscale = blockIdx.y ? ((float)NB2 / 100.0f) : ((float)NB2 / 180.0f);

    // zero bins
    #pragma unroll
    for (int q = 0; q < BPT2; q++) histu[tid + q * T3] = 0u;

    // load 16 d + 16 e per thread; key12 in high bits, e payload as u32 fixed point
    unsigned key[EPT];
    unsigned eu[EPT];
    {
        const float4* drow4 = (const float4*)&dmat[(size_t)row * N];
        const uint2* erow2 = (const uint2*)&E[(size_t)row * N];
        #pragma unroll
        for (int c4 = 0; c4 < 4; c4++) {
            float4 v = drow4[c4 * 256 + tid];
            uint2 e2 = erow2[c4 * 256 + tid];
            float dv[4] = {v.x, v.y, v.z, v.w};
            unsigned eb[4] = {e2.x << 16, e2.x & 0xffff0000u, e2.y << 16, e2.y & 0xffff0000u};
            #pragma unroll
            for (int idx = 0; idx < 4; idx++) {
                int dk = (int)(dv[idx] * kscale);
                key[c4 * 4 + idx] = (unsigned)min(max(dk, 0), NB2 - 1);
                float e = __uint_as_float(eb[idx]);
                eu[c4 * 4 + idx] = (unsigned)__float2uint_rn(e * ESCALE);
            }
        }
    }
    __syncthreads();   // bins zeroed

    // 1) histogram e-sums, native integer LDS atomics
    #pragma unroll
    for (int q = 0; q < EPT; q++)
        atomicAdd(&histu[key[q]], eu[q]);
    __syncthreads();

    // 2) inclusive suffix scan over 4096 bins (16 contiguous per thread), in float
    int base = tid * BPT2;
    {
        float s[BPT2];
        #pragma unroll
        for (int u = 0; u < 4; u++) {
            uint4 b = *(const uint4*)&histu[base + u * 4];
            s[u * 4 + 0] = (float)b.x * EINV;
            s[u * 4 + 1] = (float)b.y * EINV;
            s[u * 4 + 2] = (float)b.z * EINV;
            s[u * 4 + 3] = (float)b.w * EINV;
        }
        float t = 0.f;
        #pragma unroll
        for (int q = BPT2 - 1; q >= 0; q--) { t += s[q]; s[q] = t; }  // in-thread suffix
        float incl = t;
        #pragma unroll
        for (int off = 1; off < 64; off <<= 1) {
            float v = __shfl_down(incl, off);
            if (lane + off < 64) incl += v;
        }
        if (lane == 0) waveTot[wave] = incl;
        __syncthreads();
        float beyond = 0.f;
        for (int w = wave + 1; w < 4; w++) beyond += waveTot[w];
        float add = beyond + (incl - t);   // sum over all bins after this thread's range
        #pragma unroll
        for (int q = 0; q < BPT2; q++) s[q] += add;
        #pragma unroll
        for (int u = 0; u < 4; u++)
            *(float4*)&histf[base + u * 4] = *(const float4*)&s[u * 4];
    }
    __syncthreads();

    // 3) per-element: S_k = histf[key_k]; accumulate log
    float localSum = 0.f;
    #pragma unroll
    for (int q = 0; q < EPT; q++) {
        int j = (q >> 2) * 1024 + tid * 4 + (q & 3);
        if (j == row) continue;          // diagonal k dropped
        localSum += __logf(histf[key[q]]);
    }

    #pragma unroll
    for (int off = 32; off > 0; off >>= 1) localSum += __shfl_down(localSum, off);
    if (lane == 0) waveRed[wave] = localSum;
    __syncthreads();
    if (tid == 0)
        atomicAdd(&acc[1], (double)(waveRed[0] + waveRed[1] + waveRed[2] + waveRed[3]));
}

// ---------------- final: combine ----------------
__global__ void final_kernel(const double* __restrict__ acc, float* __restrict__ out) {
    double denom = (double)N * (double)(N - 1);
    out[0] = (float)(-(acc[0] - 0.5 * acc[1]) / denom);
}

extern "C" void kernel_launch(void* const* d_in, const int* in_sizes, int n_in,
                              void* d_out, int out_size, void* d_ws, size_t ws_size,
                              hipStream_t stream) {
    const float* theta = (const float*)d_in[0];
    const float* shift = (const float*)d_in[1];
    const float* feat  = (const float*)d_in[2];
    float* out = (float*)d_out;

    char* ws = (char*)d_ws;
    double* acc = (double*)(ws + WS_ACC_OFF);
    float* x2 = (float*)(ws + WS_X2_OFF);
    __hip_bfloat16* E = (__hip_bfloat16*)(ws + WS_E_OFF);

    hipMemsetAsync(acc, 0, 2 * sizeof(double), stream);
    x2_kernel<<<N, 64, 0, stream>>>(feat, x2);
    gram_kernel<<<dim3(32, 32), 256, 0, stream>>>(feat, x2, E, acc);
    lms_kernel<<<dim3(N, 2), T3, 0, stream>>>(E, theta, shift, acc);
    final_kernel<<<1, 1, 0, stream>>>(acc, out);
}